// Round 1
// baseline (406.105 us; speedup 1.0000x reference)
//
#include <hip/hip_runtime.h>

#define T_SEQ 128
#define NF 256
#define NH 30
#define NG 120           // 4*NH
#define NBATCH 1024
#define M_ROWS (NBATCH * T_SEQ)   // 131072

// ws layout (floats):
//   [0, 32768)       wT  : [256][128]  w_ih0 transposed, zero-padded cols
//   [32768, 32896)   bias0c[128] = b_ih0 + b_hh0, zero-padded
//   [33024, ...)     xg  : [M_ROWS][120]
#define WT_OFF 0
#define B0_OFF 32768
#define XG_OFF 33024

// ---------------------------------------------------------------- helpers
__device__ __forceinline__ float rl(float v, int j) {
  // broadcast lane j's value of v (SGPR result -> scalar operand in FMAs)
  return __int_as_float(__builtin_amdgcn_readlane(__float_as_int(v), j));
}

__device__ __forceinline__ float fast_rcp(float x) {
  return __builtin_amdgcn_rcpf(x);
}

// sigmoid(x) = 1/(1+exp(-x)); tanh(x) = 2/(1+exp(-2x)) - 1
// unified: r = 1/(1+exp(-kIn*x)); out = kOut*r + cOut
__device__ __forceinline__ float act_mix(float x, float kIn, float kOut, float cOut) {
  float e = __expf(-kIn * x);
  float r = fast_rcp(1.0f + e);
  return fmaf(kOut, r, cOut);
}

__device__ __forceinline__ float tanh_fast(float x) {
  float e = __expf(-2.0f * x);
  float r = fast_rcp(1.0f + e);
  return fmaf(2.0f, r, -1.0f);
}

// ---------------------------------------------------------------- prep
__global__ void prep_kernel(const float* __restrict__ w_ih0,
                            const float* __restrict__ b_ih0,
                            const float* __restrict__ b_hh0,
                            float* __restrict__ ws) {
  int gid = blockIdx.x * 256 + threadIdx.x;
  if (gid < 256 * 128) {
    int k = gid >> 7;
    int g = gid & 127;
    ws[WT_OFF + gid] = (g < NG) ? w_ih0[g * NF + k] : 0.0f;
  }
  if (gid < 128) {
    ws[B0_OFF + gid] = (gid < NG) ? (b_ih0[gid] + b_hh0[gid]) : 0.0f;
  }
}

// ---------------------------------------------------------------- GEMM: xg = x @ w_ih0^T + bias
// block = 256 threads (4 waves). Block computes 64 rows x 120 gates.
// wave w handles gate chunk [32w, 32w+32) (wave 3: last 24 valid).
// lane = row. x tile staged in LDS transposed [k][row] (conflict-free reads).
// w read wave-uniformly -> s_load + SGPR-operand FMAs.
__global__ __launch_bounds__(256) void gemm_xg(const float* __restrict__ x,
                                               const float* __restrict__ wsro,
                                               float* __restrict__ xg) {
  __shared__ float lds_x[64 * 64];  // [k][row]
  const int tid = threadIdx.x;
  const int lane = tid & 63;
  const int wave = tid >> 6;
  const int rowbase = blockIdx.x * 64;
  const float* __restrict__ wT = wsro + WT_OFF;
  const float* __restrict__ bias = wsro + B0_OFF;
  const int g0u = __builtin_amdgcn_readfirstlane(wave * 32);

  float acc[32];
#pragma unroll
  for (int j = 0; j < 32; ++j) acc[j] = bias[g0u + j];

  // staging map: 4 threads per row, 16 k each (64B contiguous per thread)
  const int sr = tid >> 2;
  const int sk = (tid & 3) * 16;

  for (int k0 = 0; k0 < NF; k0 += 64) {
    const float4* __restrict__ src =
        reinterpret_cast<const float4*>(x + (size_t)(rowbase + sr) * NF + k0 + sk);
#pragma unroll
    for (int j = 0; j < 4; ++j) {
      float4 v = src[j];
      int kk = sk + j * 4;
      lds_x[(kk + 0) * 64 + sr] = v.x;
      lds_x[(kk + 1) * 64 + sr] = v.y;
      lds_x[(kk + 2) * 64 + sr] = v.z;
      lds_x[(kk + 3) * 64 + sr] = v.w;
    }
    __syncthreads();

#pragma unroll 8
    for (int k = 0; k < 64; ++k) {
      float xk = lds_x[k * 64 + lane];
      const float* __restrict__ wk = wT + (size_t)(k0 + k) * 128 + g0u;
#pragma unroll
      for (int j = 0; j < 32; ++j) acc[j] = fmaf(xk, wk[j], acc[j]);
    }
    __syncthreads();
  }

  const int row = rowbase + lane;
  float* __restrict__ dst = xg + (size_t)row * NG + g0u;
  const int n4 = (g0u == 96) ? 6 : 8;  // wave 3 stores only 24 gates
  for (int i = 0; i < n4; ++i) {
    float4 v = make_float4(acc[4 * i], acc[4 * i + 1], acc[4 * i + 2], acc[4 * i + 3]);
    reinterpret_cast<float4*>(dst)[i] = v;
  }
}

// ---------------------------------------------------------------- fused 2-layer recurrence + linear
// one wave per batch element. lane l<30: gates (i_l, f_l); lane 32+l: (g_l, o_l).
// h broadcast via v_readlane; all weights in per-lane VGPRs; no LDS, no barriers.
__global__ __launch_bounds__(64) void lstm_fused(const float* __restrict__ xg,
                                                 const float* __restrict__ w_hh0,
                                                 const float* __restrict__ w_ih1,
                                                 const float* __restrict__ w_hh1,
                                                 const float* __restrict__ b_ih1,
                                                 const float* __restrict__ b_hh1,
                                                 const float* __restrict__ w_lin,
                                                 const float* __restrict__ b_lin,
                                                 float* __restrict__ out) {
  const int b = blockIdx.x;
  const int lane = threadIdx.x;
  const bool hiHalf = lane >= 32;
  const int l = hiHalf ? (lane - 32) : lane;
  const int lc = (l < NH) ? l : (NH - 1);       // clamp idle lanes 30,31,62,63
  const int gA = hiHalf ? (60 + lc) : lc;       // i or g
  const int gB = gA + NH;                       // f or o

  // activation selectors (per-lane constants)
  const float kInA = hiHalf ? 2.0f : 1.0f;      // gate A: hi=tanh, lo=sigmoid
  const float kOutA = hiHalf ? 2.0f : 1.0f;
  const float cOutA = hiHalf ? -1.0f : 0.0f;

  float wA0[NH], wB0[NH], vA1[NH], vB1[NH], uA1[NH], uB1[NH];
#pragma unroll
  for (int j = 0; j < NH; ++j) {
    wA0[j] = w_hh0[gA * NH + j];
    wB0[j] = w_hh0[gB * NH + j];
    vA1[j] = w_ih1[gA * NH + j];
    vB1[j] = w_ih1[gB * NH + j];
    uA1[j] = w_hh1[gA * NH + j];
    uB1[j] = w_hh1[gB * NH + j];
  }
  const float bA1 = b_ih1[gA] + b_hh1[gA];
  const float bB1 = b_ih1[gB] + b_hh1[gB];

  float h0 = 0.0f, c0 = 0.0f, h1 = 0.0f, c1 = 0.0f, acc = 0.0f;
  const float* __restrict__ xgb = xg + (size_t)b * T_SEQ * NG;

  // depth-3 prefetch ring
  float xa[4], xb[4], wlr[4];
#pragma unroll
  for (int p = 0; p < 3; ++p) {
    xa[p] = xgb[p * NG + gA];
    xb[p] = xgb[p * NG + gB];
    wlr[p] = w_lin[p * NH + lc];
  }

#pragma unroll 4
  for (int t = 0; t < T_SEQ; ++t) {
    const int cur = t & 3;
    const int nxt = (t + 3) & 3;
    const int tp = (t + 3 < T_SEQ) ? (t + 3) : (T_SEQ - 1);
    float pxa = xgb[tp * NG + gA];
    float pxb = xgb[tp * NG + gB];
    float pwl = w_lin[tp * NH + lc];

    // ---- layer 0 gates (split accumulators for ILP)
    float sA = xa[cur], sB = xb[cur], sA2 = 0.0f, sB2 = 0.0f;
#pragma unroll
    for (int j = 0; j < NH; j += 2) {
      float hj = rl(h0, j);
      float hj1 = rl(h0, j + 1);
      sA = fmaf(hj, wA0[j], sA);
      sB = fmaf(hj, wB0[j], sB);
      sA2 = fmaf(hj1, wA0[j + 1], sA2);
      sB2 = fmaf(hj1, wB0[j + 1], sB2);
    }
    sA += sA2;
    sB += sB2;
    float aA = act_mix(sA, kInA, kOutA, cOutA);  // lo: i=sig, hi: g=tanh
    float aB = act_mix(sB, 1.0f, 1.0f, 0.0f);    // f / o = sigmoid
    float gg = __shfl_down(aA, 32);
    float oo = __shfl_down(aB, 32);
    c0 = fmaf(aB, c0, aA * gg);                  // f*c + i*g (valid lanes<30)
    h0 = oo * tanh_fast(c0);

    // ---- layer 1 gates: on-the-fly input GEMM (h0) + recurrent (h1)
    float sv = bA1, sv2 = 0.0f, svB = bB1, svB2 = 0.0f;
    float su = 0.0f, su2 = 0.0f, suB = 0.0f, suB2 = 0.0f;
#pragma unroll
    for (int j = 0; j < NH; j += 2) {
      float xj = rl(h0, j);
      float xj1 = rl(h0, j + 1);
      float hj = rl(h1, j);
      float hj1 = rl(h1, j + 1);
      sv = fmaf(xj, vA1[j], sv);
      svB = fmaf(xj, vB1[j], svB);
      sv2 = fmaf(xj1, vA1[j + 1], sv2);
      svB2 = fmaf(xj1, vB1[j + 1], svB2);
      su = fmaf(hj, uA1[j], su);
      suB = fmaf(hj, uB1[j], suB);
      su2 = fmaf(hj1, uA1[j + 1], su2);
      suB2 = fmaf(hj1, uB1[j + 1], suB2);
    }
    float s1A = (sv + sv2) + (su + su2);
    float s1B = (svB + svB2) + (suB + suB2);
    float a1A = act_mix(s1A, kInA, kOutA, cOutA);
    float a1B = act_mix(s1B, 1.0f, 1.0f, 0.0f);
    float gg1 = __shfl_down(a1A, 32);
    float oo1 = __shfl_down(a1B, 32);
    c1 = fmaf(a1B, c1, a1A * gg1);
    h1 = oo1 * tanh_fast(c1);

    acc = fmaf(h1, wlr[cur], acc);  // final linear, valid lanes<30

    xa[nxt] = pxa;
    xb[nxt] = pxb;
    wlr[nxt] = pwl;
  }

  if (lane >= NH) acc = 0.0f;  // only low-half lanes<30 hold valid h2
#pragma unroll
  for (int off = 32; off > 0; off >>= 1) acc += __shfl_xor(acc, off);
  if (lane == 0) out[b] = acc + b_lin[0];
}

// ---------------------------------------------------------------- launch
extern "C" void kernel_launch(void* const* d_in, const int* in_sizes, int n_in,
                              void* d_out, int out_size, void* d_ws, size_t ws_size,
                              hipStream_t stream) {
  (void)in_sizes; (void)n_in; (void)out_size; (void)ws_size;
  const float* x     = (const float*)d_in[0];
  const float* w_ih0 = (const float*)d_in[1];
  const float* w_hh0 = (const float*)d_in[2];
  const float* b_ih0 = (const float*)d_in[3];
  const float* b_hh0 = (const float*)d_in[4];
  const float* w_ih1 = (const float*)d_in[5];
  const float* w_hh1 = (const float*)d_in[6];
  const float* b_ih1 = (const float*)d_in[7];
  const float* b_hh1 = (const float*)d_in[8];
  const float* w_lin = (const float*)d_in[9];
  const float* b_lin = (const float*)d_in[10];
  float* ws  = (float*)d_ws;
  float* out = (float*)d_out;

  prep_kernel<<<128, 256, 0, stream>>>(w_ih0, b_ih0, b_hh0, ws);
  gemm_xg<<<M_ROWS / 64, 256, 0, stream>>>(x, ws, ws + XG_OFF);
  lstm_fused<<<NBATCH, 64, 0, stream>>>(ws + XG_OFF, w_hh0, w_ih1, w_hh1,
                                        b_ih1, b_hh1, w_lin, b_lin, out);
}

// Round 2
// 291.477 us; speedup vs baseline: 1.3933x; 1.3933x over previous
//
#include <hip/hip_runtime.h>

#define T_SEQ 128
#define NF 256
#define NH 30
#define NG 120           // 4*NH
#define NBATCH 1024
#define M_ROWS (NBATCH * T_SEQ)   // 131072

// ws byte offsets:
//   [0, 512)          bias0c[128] = b_ih0 + b_hh0, zero-padded to 128
//   [1024, 66560)     Bfrag_hi: [8 ktiles][8 subtiles][64 lanes][8 bf16]  (64 KB)
//   [66560, 132096)   Bfrag_lo: same shape (64 KB)
//   [132096, ...)     xg: [M_ROWS][120] fp32 (62.9 MB)
#define BIAS_OFF 0
#define BHI_OFF  1024
#define BLO_OFF  (BHI_OFF + 65536)
#define XG_OFF_B (BLO_OFF + 65536)   // 132096 bytes = 33024 floats

typedef __attribute__((ext_vector_type(8))) short short8;
typedef __attribute__((ext_vector_type(4))) float float4v;

// ---------------------------------------------------------------- helpers
__device__ __forceinline__ short bf16_of(float f) {
  union { float f; unsigned u; } v; v.f = f;
  unsigned r = v.u + 0x7fffu + ((v.u >> 16) & 1u);  // RNE
  return (short)(r >> 16);
}
__device__ __forceinline__ float f_of_bf16(short s) {
  union { unsigned u; float f; } v; v.u = ((unsigned)(unsigned short)s) << 16;
  return v.f;
}

__device__ __forceinline__ float rl(float v, int j) {
  return __int_as_float(__builtin_amdgcn_readlane(__float_as_int(v), j));
}
__device__ __forceinline__ float fast_rcp(float x) { return __builtin_amdgcn_rcpf(x); }
__device__ __forceinline__ float act_mix(float x, float kIn, float kOut, float cOut) {
  float e = __expf(-kIn * x);
  float r = fast_rcp(1.0f + e);
  return fmaf(kOut, r, cOut);
}
__device__ __forceinline__ float tanh_fast(float x) {
  float e = __expf(-2.0f * x);
  float r = fast_rcp(1.0f + e);
  return fmaf(2.0f, r, -1.0f);
}

// ---------------------------------------------------------------- prep
// Splits w_ih0 into bf16 hi/lo planes laid out in MFMA B-operand fragment
// order: frag(t,s,lane)[j] = w[n = s*16 + (lane&15)][k = t*32 + (lane>>4)*8 + j]
__global__ void prep_kernel(const float* __restrict__ w_ih0,
                            const float* __restrict__ b_ih0,
                            const float* __restrict__ b_hh0,
                            unsigned char* __restrict__ ws) {
  int gid = blockIdx.x * 256 + threadIdx.x;   // 0..4095 = (t*8+s)*64 + lane
  float* bias = (float*)(ws + BIAS_OFF);
  if (gid < 128) bias[gid] = (gid < NG) ? (b_ih0[gid] + b_hh0[gid]) : 0.0f;

  int lane = gid & 63;
  int ts = gid >> 6;
  int t = ts >> 3, s = ts & 7;
  int n = s * 16 + (lane & 15);
  int k0 = t * 32 + (lane >> 4) * 8;

  short8 hi, lo;
#pragma unroll
  for (int j = 0; j < 8; ++j) {
    float v = (n < NG) ? w_ih0[n * NF + k0 + j] : 0.0f;
    short h = bf16_of(v);
    hi[j] = h;
    lo[j] = bf16_of(v - f_of_bf16(h));
  }
  *(short8*)(ws + BHI_OFF + (size_t)gid * 16) = hi;
  *(short8*)(ws + BLO_OFF + (size_t)gid * 16) = lo;
}

// ---------------------------------------------------------------- GEMM: xg = x @ w_ih0^T + bias (split-bf16 MFMA)
// block = 256 (4 waves). Block tile: 128 rows x 128 cols. Wave: 32 rows (2
// rowgroups of 16) x 128 cols (8 subtiles of 16). K = 256 in 8 ktiles of 32.
// A: direct global->reg loads + in-register hi/lo split (x read exactly once).
// B: prep-split fragments staged global->LDS via global_load_lds(16B),
//    double-buffered, read as lane-contiguous ds_read_b128.
__global__ __launch_bounds__(256, 3) void gemm_xg(const float* __restrict__ x,
                                                  const unsigned char* __restrict__ ws,
                                                  float* __restrict__ xg) {
  __shared__ short lds_B[2][8 * 2 * 64 * 8];   // [buf][(s*2+plane)*64 + lane][8]
  const int tid = threadIdx.x;
  const int lane = tid & 63;
  const int wave = tid >> 6;
  const int r15 = lane & 15;
  const int quad = lane >> 4;
  const int rowbase = blockIdx.x * 128 + wave * 32;

  const short* __restrict__ Bhi = (const short*)(ws + BHI_OFF);
  const short* __restrict__ Blo = (const short*)(ws + BLO_OFF);
  const float* __restrict__ bias = (const float*)(ws + BIAS_OFF);

  // accumulators pre-loaded with bias (broadcast across the 4 row-regs)
  float4v acc[2][8];
#pragma unroll
  for (int s = 0; s < 8; ++s) {
    float b = bias[s * 16 + r15];
    float4v bv = {b, b, b, b};
    acc[0][s] = bv;
    acc[1][s] = bv;
  }

  const float* xptr[2];
  xptr[0] = x + (size_t)(rowbase + r15) * NF + quad * 8;
  xptr[1] = x + (size_t)(rowbase + 16 + r15) * NF + quad * 8;

  // --- stage B ktile 0 into buf 0 (wave w handles subtiles 2w, 2w+1)
#pragma unroll
  for (int i = 0; i < 2; ++i) {
    int s = wave * 2 + i;
    const short* ghi = Bhi + ((size_t)(0 * 8 + s) * 64 + lane) * 8;
    const short* glo = Blo + ((size_t)(0 * 8 + s) * 64 + lane) * 8;
    short* lhi = &lds_B[0][(s * 2 + 0) * 64 * 8];
    short* llo = &lds_B[0][(s * 2 + 1) * 64 * 8];
    __builtin_amdgcn_global_load_lds((const __attribute__((address_space(1))) void*)ghi,
                                     (__attribute__((address_space(3))) void*)lhi, 16, 0, 0);
    __builtin_amdgcn_global_load_lds((const __attribute__((address_space(1))) void*)glo,
                                     (__attribute__((address_space(3))) void*)llo, 16, 0, 0);
  }

  // --- load + convert A ktile 0
  short8 ahi[2], alo[2];
#pragma unroll
  for (int g = 0; g < 2; ++g) {
    float4 p0 = *(const float4*)(xptr[g] + 0);
    float4 p1 = *(const float4*)(xptr[g] + 4);
    float f[8] = {p0.x, p0.y, p0.z, p0.w, p1.x, p1.y, p1.z, p1.w};
#pragma unroll
    for (int j = 0; j < 8; ++j) {
      short h = bf16_of(f[j]);
      ahi[g][j] = h;
      alo[g][j] = bf16_of(f[j] - f_of_bf16(h));
    }
  }
  __syncthreads();

  for (int t = 0; t < 8; ++t) {
    const int buf = t & 1;
    float4 anx[2][2];
    if (t < 7) {
      // stage B ktile t+1 into the other buffer
#pragma unroll
      for (int i = 0; i < 2; ++i) {
        int s = wave * 2 + i;
        const short* ghi = Bhi + ((size_t)((t + 1) * 8 + s) * 64 + lane) * 8;
        const short* glo = Blo + ((size_t)((t + 1) * 8 + s) * 64 + lane) * 8;
        short* lhi = &lds_B[buf ^ 1][(s * 2 + 0) * 64 * 8];
        short* llo = &lds_B[buf ^ 1][(s * 2 + 1) * 64 * 8];
        __builtin_amdgcn_global_load_lds((const __attribute__((address_space(1))) void*)ghi,
                                         (__attribute__((address_space(3))) void*)lhi, 16, 0, 0);
        __builtin_amdgcn_global_load_lds((const __attribute__((address_space(1))) void*)glo,
                                         (__attribute__((address_space(3))) void*)llo, 16, 0, 0);
      }
      // prefetch A ktile t+1
#pragma unroll
      for (int g = 0; g < 2; ++g) {
        anx[g][0] = *(const float4*)(xptr[g] + (t + 1) * 32);
        anx[g][1] = *(const float4*)(xptr[g] + (t + 1) * 32 + 4);
      }
    }

#pragma unroll
    for (int s = 0; s < 8; ++s) {
      const short8 bh = *(const short8*)&lds_B[buf][((s * 2 + 0) * 64 + lane) * 8];
      const short8 bl = *(const short8*)&lds_B[buf][((s * 2 + 1) * 64 + lane) * 8];
#pragma unroll
      for (int g = 0; g < 2; ++g) {
        acc[g][s] = __builtin_amdgcn_mfma_f32_16x16x32_bf16(ahi[g], bh, acc[g][s], 0, 0, 0);
        acc[g][s] = __builtin_amdgcn_mfma_f32_16x16x32_bf16(ahi[g], bl, acc[g][s], 0, 0, 0);
        acc[g][s] = __builtin_amdgcn_mfma_f32_16x16x32_bf16(alo[g], bh, acc[g][s], 0, 0, 0);
      }
    }

    if (t < 7) {
#pragma unroll
      for (int g = 0; g < 2; ++g) {
        float f[8] = {anx[g][0].x, anx[g][0].y, anx[g][0].z, anx[g][0].w,
                      anx[g][1].x, anx[g][1].y, anx[g][1].z, anx[g][1].w};
#pragma unroll
        for (int j = 0; j < 8; ++j) {
          short h = bf16_of(f[j]);
          ahi[g][j] = h;
          alo[g][j] = bf16_of(f[j] - f_of_bf16(h));
        }
      }
    }
    __syncthreads();
  }

  // epilogue: C/D layout col = lane&15, row = quad*4 + reg
#pragma unroll
  for (int g = 0; g < 2; ++g) {
    const int row0 = rowbase + g * 16 + quad * 4;
#pragma unroll
    for (int s = 0; s < 8; ++s) {
      const int col = s * 16 + r15;
      if (col < NG) {
#pragma unroll
        for (int i = 0; i < 4; ++i) {
          xg[(size_t)(row0 + i) * NG + col] = acc[g][s][i];
        }
      }
    }
  }
}

// ---------------------------------------------------------------- fused 2-layer recurrence + linear
__global__ __launch_bounds__(64) void lstm_fused(const float* __restrict__ xg,
                                                 const float* __restrict__ w_hh0,
                                                 const float* __restrict__ w_ih1,
                                                 const float* __restrict__ w_hh1,
                                                 const float* __restrict__ b_ih1,
                                                 const float* __restrict__ b_hh1,
                                                 const float* __restrict__ w_lin,
                                                 const float* __restrict__ b_lin,
                                                 float* __restrict__ out) {
  const int b = blockIdx.x;
  const int lane = threadIdx.x;
  const bool hiHalf = lane >= 32;
  const int l = hiHalf ? (lane - 32) : lane;
  const int lc = (l < NH) ? l : (NH - 1);
  const int gA = hiHalf ? (60 + lc) : lc;
  const int gB = gA + NH;

  const float kInA = hiHalf ? 2.0f : 1.0f;
  const float kOutA = hiHalf ? 2.0f : 1.0f;
  const float cOutA = hiHalf ? -1.0f : 0.0f;

  float wA0[NH], wB0[NH], vA1[NH], vB1[NH], uA1[NH], uB1[NH];
#pragma unroll
  for (int j = 0; j < NH; ++j) {
    wA0[j] = w_hh0[gA * NH + j];
    wB0[j] = w_hh0[gB * NH + j];
    vA1[j] = w_ih1[gA * NH + j];
    vB1[j] = w_ih1[gB * NH + j];
    uA1[j] = w_hh1[gA * NH + j];
    uB1[j] = w_hh1[gB * NH + j];
  }
  const float bA1 = b_ih1[gA] + b_hh1[gA];
  const float bB1 = b_ih1[gB] + b_hh1[gB];

  float h0 = 0.0f, c0 = 0.0f, h1 = 0.0f, c1 = 0.0f, acc = 0.0f;
  const float* __restrict__ xgb = xg + (size_t)b * T_SEQ * NG;

  float xa[4], xb[4], wlr[4];
#pragma unroll
  for (int p = 0; p < 3; ++p) {
    xa[p] = xgb[p * NG + gA];
    xb[p] = xgb[p * NG + gB];
    wlr[p] = w_lin[p * NH + lc];
  }

#pragma unroll 4
  for (int t = 0; t < T_SEQ; ++t) {
    const int cur = t & 3;
    const int nxt = (t + 3) & 3;
    const int tp = (t + 3 < T_SEQ) ? (t + 3) : (T_SEQ - 1);
    float pxa = xgb[tp * NG + gA];
    float pxb = xgb[tp * NG + gB];
    float pwl = w_lin[tp * NH + lc];

    float sA = xa[cur], sB = xb[cur], sA2 = 0.0f, sB2 = 0.0f;
#pragma unroll
    for (int j = 0; j < NH; j += 2) {
      float hj = rl(h0, j);
      float hj1 = rl(h0, j + 1);
      sA = fmaf(hj, wA0[j], sA);
      sB = fmaf(hj, wB0[j], sB);
      sA2 = fmaf(hj1, wA0[j + 1], sA2);
      sB2 = fmaf(hj1, wB0[j + 1], sB2);
    }
    sA += sA2;
    sB += sB2;
    float aA = act_mix(sA, kInA, kOutA, cOutA);
    float aB = act_mix(sB, 1.0f, 1.0f, 0.0f);
    float gg = __shfl_down(aA, 32);
    float oo = __shfl_down(aB, 32);
    c0 = fmaf(aB, c0, aA * gg);
    h0 = oo * tanh_fast(c0);

    float sv = bA1, sv2 = 0.0f, svB = bB1, svB2 = 0.0f;
    float su = 0.0f, su2 = 0.0f, suB = 0.0f, suB2 = 0.0f;
#pragma unroll
    for (int j = 0; j < NH; j += 2) {
      float xj = rl(h0, j);
      float xj1 = rl(h0, j + 1);
      float hj = rl(h1, j);
      float hj1 = rl(h1, j + 1);
      sv = fmaf(xj, vA1[j], sv);
      svB = fmaf(xj, vB1[j], svB);
      sv2 = fmaf(xj1, vA1[j + 1], sv2);
      svB2 = fmaf(xj1, vB1[j + 1], svB2);
      su = fmaf(hj, uA1[j], su);
      suB = fmaf(hj, uB1[j], suB);
      su2 = fmaf(hj1, uA1[j + 1], su2);
      suB2 = fmaf(hj1, uB1[j + 1], suB2);
    }
    float s1A = (sv + sv2) + (su + su2);
    float s1B = (svB + svB2) + (suB + suB2);
    float a1A = act_mix(s1A, kInA, kOutA, cOutA);
    float a1B = act_mix(s1B, 1.0f, 1.0f, 0.0f);
    float gg1 = __shfl_down(a1A, 32);
    float oo1 = __shfl_down(a1B, 32);
    c1 = fmaf(a1B, c1, a1A * gg1);
    h1 = oo1 * tanh_fast(c1);

    acc = fmaf(h1, wlr[cur], acc);

    xa[nxt] = pxa;
    xb[nxt] = pxb;
    wlr[nxt] = pwl;
  }

  if (lane >= NH) acc = 0.0f;
#pragma unroll
  for (int off = 32; off > 0; off >>= 1) acc += __shfl_xor(acc, off);
  if (lane == 0) out[b] = acc + b_lin[0];
}

// ---------------------------------------------------------------- launch
extern "C" void kernel_launch(void* const* d_in, const int* in_sizes, int n_in,
                              void* d_out, int out_size, void* d_ws, size_t ws_size,
                              hipStream_t stream) {
  (void)in_sizes; (void)n_in; (void)out_size; (void)ws_size;
  const float* x     = (const float*)d_in[0];
  const float* w_ih0 = (const float*)d_in[1];
  const float* w_hh0 = (const float*)d_in[2];
  const float* b_ih0 = (const float*)d_in[3];
  const float* b_hh0 = (const float*)d_in[4];
  const float* w_ih1 = (const float*)d_in[5];
  const float* w_hh1 = (const float*)d_in[6];
  const float* b_ih1 = (const float*)d_in[7];
  const float* b_hh1 = (const float*)d_in[8];
  const float* w_lin = (const float*)d_in[9];
  const float* b_lin = (const float*)d_in[10];
  unsigned char* ws = (unsigned char*)d_ws;
  float* out = (float*)d_out;
  float* xg = (float*)(ws + XG_OFF_B);

  prep_kernel<<<16, 256, 0, stream>>>(w_ih0, b_ih0, b_hh0, ws);
  gemm_xg<<<M_ROWS / 128, 256, 0, stream>>>(x, ws, xg);
  lstm_fused<<<NBATCH, 64, 0, stream>>>(xg, w_hh0, w_ih1, w_hh1,
                                        b_ih1, b_hh1, w_lin, b_lin, out);
}